// Round 4
// baseline (500.274 us; speedup 1.0000x reference)
//
#include <hip/hip_runtime.h>

typedef int v4i __attribute__((ext_vector_type(4)));

#define THREADS 256
#define EPT 64                        // edges per thread (held in registers)
#define WBLK (THREADS * EPT)          // 16384 edges per block
#define PART_BITS 18                  // 262144 nodes per LDS partition
#define PART_NODES (1 << PART_BITS)
#define PART_WORDS (PART_NODES / 16)  // 16384 uint32 = 64 KB
#define NPART 4                       // 4 * 262144 = 1048576 nodes
#define TBL 450                       // NUM_RELS * 9

__global__ void zero_kernel(float* __restrict__ out, int n) {
    int i = blockIdx.x * blockDim.x + threadIdx.x;
    if (i < n) out[i] = 0.0f;
}

// Pack node_type (values 0..2) into 2 bits/node: 16 nodes per uint32 (256 KB).
__global__ void pack_nt_kernel(const int* __restrict__ nt,
                               unsigned int* __restrict__ packed,
                               int nwords, int N) {
    int i = blockIdx.x * blockDim.x + threadIdx.x;
    if (i >= nwords) return;
    unsigned int word = 0;
    int base = i * 16;
    if (base + 16 <= N) {
        #pragma unroll
        for (int j = 0; j < 4; ++j) {
            int4 v = *reinterpret_cast<const int4*>(nt + base + j * 4);
            word |= (unsigned)(v.x & 3) << (2 * (j * 4 + 0));
            word |= (unsigned)(v.y & 3) << (2 * (j * 4 + 1));
            word |= (unsigned)(v.z & 3) << (2 * (j * 4 + 2));
            word |= (unsigned)(v.w & 3) << (2 * (j * 4 + 3));
        }
    } else {
        for (int j = 0; base + j < N; ++j)
            word |= (unsigned)(nt[base + j] & 3) << (2 * j);
    }
    packed[i] = word;
}

// LDS-partitioned gather: the packed node-type table (256 KB) is processed in
// four 64 KB LDS-resident partitions. Node-type lookups become ds_read
// (no TCP miss slots). Edge endpoints + partial enc stay in registers
// (statically indexed; EPT=64). 2 blocks/CU so one block's table fill
// (global, TCP) overlaps the other's LDS gather phase.
__launch_bounds__(THREADS, 2)
__global__ void edge_score_lds(const unsigned int* __restrict__ pnt,
                               const int* __restrict__ edge_type,
                               const int* __restrict__ esrc,
                               const int* __restrict__ edst,
                               const int* __restrict__ edge_batch,
                               const float* __restrict__ wtab,
                               float* __restrict__ out) {
    __shared__ unsigned int lds[PART_WORDS];   // 64 KB

    const long base = (long)blockIdx.x * WBLK + (long)threadIdx.x * EPT;

    int sv[EPT], dv[EPT], enc[EPT];

    // Stream edges once (nontemporal: don't pollute L1/L2 with dead lines).
    #pragma unroll
    for (int j = 0; j < EPT / 4; ++j) {
        v4i et = __builtin_nontemporal_load(reinterpret_cast<const v4i*>(edge_type + base + j * 4));
        v4i s  = __builtin_nontemporal_load(reinterpret_cast<const v4i*>(esrc      + base + j * 4));
        v4i d  = __builtin_nontemporal_load(reinterpret_cast<const v4i*>(edst      + base + j * 4));
        #pragma unroll
        for (int q = 0; q < 4; ++q) {
            enc[j * 4 + q] = et[q] * 9;
            sv[j * 4 + q]  = s[q];
            dv[j * 4 + q]  = d[q];
        }
    }

    #pragma unroll
    for (int p = 0; p < NPART; ++p) {
        // Cooperative fill of partition p (normal loads: keep pnt L2-hot).
        {
            const v4i* src = reinterpret_cast<const v4i*>(pnt + p * PART_WORDS);
            v4i* dst = reinterpret_cast<v4i*>(lds);
            #pragma unroll
            for (int i = 0; i < PART_WORDS / 4 / THREADS; ++i)   // 16 iters
                dst[i * THREADS + threadIdx.x] = src[i * THREADS + threadIdx.x];
        }
        __syncthreads();

        // Resolve endpoints that fall in this partition (ds_read + predicate).
        #pragma unroll
        for (int k = 0; k < EPT; ++k) {
            unsigned s = (unsigned)sv[k];
            unsigned ws = lds[(s & (PART_NODES - 1)) >> 4];
            int nts = (int)((ws >> ((s & 15u) << 1)) & 3u);
            if ((s >> PART_BITS) == (unsigned)p) enc[k] += nts * 3;

            unsigned d = (unsigned)dv[k];
            unsigned wd = lds[(d & (PART_NODES - 1)) >> 4];
            int ntd = (int)((wd >> ((d & 15u) << 1)) & 3u);
            if ((d >> PART_BITS) == (unsigned)p) enc[k] += ntd;
        }
        __syncthreads();   // before next fill overwrites the table
    }

    // Table is dead: overwrite LDS head with the 450-entry weight table.
    float* lw = reinterpret_cast<float*>(lds);
    for (int i = threadIdx.x; i < TBL; i += THREADS) lw[i] = wtab[i];
    __syncthreads();

    // Segmented per-graph sum; bv streamed here (coalesced, read-once).
    float acc = 0.0f;
    int   cur = -1;
    #pragma unroll
    for (int j = 0; j < EPT / 4; ++j) {
        v4i b = __builtin_nontemporal_load(reinterpret_cast<const v4i*>(edge_batch + base + j * 4));
        #pragma unroll
        for (int q = 0; q < 4; ++q) {
            float v = lw[enc[j * 4 + q]];
            int bb = b[q];
            if (bb != cur) {
                if (cur >= 0) atomicAdd(&out[cur], acc);
                cur = bb;
                acc = 0.0f;
            }
            acc += v;
        }
    }
    if (cur >= 0) atomicAdd(&out[cur], acc);
}

// Per-edge fallback / tail kernel (direct node_type gathers; correctness path).
__global__ void edge_score_simple(const int* __restrict__ nt,
                                  const int* __restrict__ et,
                                  const int* __restrict__ es,
                                  const int* __restrict__ ed,
                                  const int* __restrict__ eb,
                                  const float* __restrict__ w,
                                  float* __restrict__ out,
                                  long e0, long E) {
    long e = e0 + (long)blockIdx.x * blockDim.x + threadIdx.x;
    if (e >= E) return;
    int enc = et[e] * 9 + nt[es[e]] * 3 + nt[ed[e]];
    atomicAdd(&out[eb[e]], w[enc]);
}

extern "C" void kernel_launch(void* const* d_in, const int* in_sizes, int n_in,
                              void* d_out, int out_size, void* d_ws, size_t ws_size,
                              hipStream_t stream) {
    const int*   node_type  = (const int*)d_in[0];
    const int*   edge_type  = (const int*)d_in[1];
    const int*   edge_index = (const int*)d_in[2];   // [2, E]: src then dst
    const int*   edge_batch = (const int*)d_in[3];
    const float* w          = (const float*)d_in[4];
    float* out = (float*)d_out;

    long N = in_sizes[0];
    long E = in_sizes[1];
    const int* esrc = edge_index;
    const int* edst = edge_index + E;

    // d_out is poisoned once and never re-poisoned between replays; we
    // accumulate with atomics, so zero it at the start of every launch.
    zero_kernel<<<(out_size + 255) / 256, 256, 0, stream>>>(out, out_size);

    int  nwords  = (int)((N + 15) / 16);
    bool fast_ok = (ws_size >= (size_t)nwords * 4) && (N <= (long)NPART * PART_NODES);

    if (fast_ok) {
        unsigned int* pnt = (unsigned int*)d_ws;
        pack_nt_kernel<<<(nwords + 255) / 256, 256, 0, stream>>>(node_type, pnt, nwords, (int)N);

        long nfull = E / WBLK;               // 1024 for E = 2^24
        long rem   = E % WBLK;               // 0 for this dataset
        if (nfull > 0)
            edge_score_lds<<<(int)nfull, THREADS, 0, stream>>>(
                pnt, edge_type, esrc, edst, edge_batch, w, out);
        if (rem > 0) {
            long e0 = nfull * WBLK;
            int  tb = (int)((rem + 255) / 256);
            edge_score_simple<<<tb, 256, 0, stream>>>(
                node_type, edge_type, esrc, edst, edge_batch, w, out, e0, E);
        }
    } else {
        int tb = (int)((E + 255) / 256);
        edge_score_simple<<<tb, 256, 0, stream>>>(
            node_type, edge_type, esrc, edst, edge_batch, w, out, 0, E);
    }
}

// Round 5
// 192.315 us; speedup vs baseline: 2.6013x; 2.6013x over previous
//
#include <hip/hip_runtime.h>

typedef int v4i __attribute__((ext_vector_type(4)));

#define THREADS 1024
#define EPT 16                        // edges per thread (held in registers)
#define WBLK (THREADS * EPT)          // 16384 edges per block
#define PART_BITS 18                  // 262144 nodes per LDS partition
#define PART_NODES (1 << PART_BITS)
#define PART_WORDS (PART_NODES / 16)  // 16384 uint32 = 64 KB
#define NPART 4                       // 4 * 262144 = 1048576 nodes
#define TBL 450                       // NUM_RELS * 9

__global__ void zero_kernel(float* __restrict__ out, int n) {
    int i = blockIdx.x * blockDim.x + threadIdx.x;
    if (i < n) out[i] = 0.0f;
}

// Pack node_type (values 0..2) into 2 bits/node: 16 nodes per uint32 (256 KB).
__global__ void pack_nt_kernel(const int* __restrict__ nt,
                               unsigned int* __restrict__ packed,
                               int nwords, int N) {
    int i = blockIdx.x * blockDim.x + threadIdx.x;
    if (i >= nwords) return;
    unsigned int word = 0;
    int base = i * 16;
    if (base + 16 <= N) {
        #pragma unroll
        for (int j = 0; j < 4; ++j) {
            int4 v = *reinterpret_cast<const int4*>(nt + base + j * 4);
            word |= (unsigned)(v.x & 3) << (2 * (j * 4 + 0));
            word |= (unsigned)(v.y & 3) << (2 * (j * 4 + 1));
            word |= (unsigned)(v.z & 3) << (2 * (j * 4 + 2));
            word |= (unsigned)(v.w & 3) << (2 * (j * 4 + 3));
        }
    } else {
        for (int j = 0; base + j < N; ++j)
            word |= (unsigned)(nt[base + j] & 3) << (2 * j);
    }
    packed[i] = word;
}

// LDS-partitioned gather. 256 KB packed node-type table processed in four
// 64 KB LDS-resident partitions; node-type lookups are ds_read (no TCP miss
// slots). Per-thread state sized to avoid spill: 3*EPT = 48 VGPRs.
// __launch_bounds__(1024) => VGPR cap 128 (16 waves must fit a CU).
__launch_bounds__(THREADS)
__global__ void edge_score_lds(const unsigned int* __restrict__ pnt,
                               const int* __restrict__ edge_type,
                               const int* __restrict__ esrc,
                               const int* __restrict__ edst,
                               const int* __restrict__ edge_batch,
                               const float* __restrict__ wtab,
                               float* __restrict__ out) {
    __shared__ unsigned int lds[PART_WORDS];   // 64 KB

    const long base = (long)blockIdx.x * WBLK + (long)threadIdx.x * EPT;

    int sv[EPT], dv[EPT], enc[EPT];

    // Stream edges once (nontemporal; coalesced 16B/lane).
    #pragma unroll
    for (int j = 0; j < EPT / 4; ++j) {
        v4i et = __builtin_nontemporal_load(reinterpret_cast<const v4i*>(edge_type + base + j * 4));
        v4i s  = __builtin_nontemporal_load(reinterpret_cast<const v4i*>(esrc      + base + j * 4));
        v4i d  = __builtin_nontemporal_load(reinterpret_cast<const v4i*>(edst      + base + j * 4));
        #pragma unroll
        for (int q = 0; q < 4; ++q) {
            enc[j * 4 + q] = et[q] * 9;
            sv[j * 4 + q]  = s[q];
            dv[j * 4 + q]  = d[q];
        }
    }

    #pragma unroll
    for (int p = 0; p < NPART; ++p) {
        // Cooperative fill of partition p (coalesced dwordx4; L2-resident src).
        {
            const v4i* src = reinterpret_cast<const v4i*>(pnt + p * PART_WORDS);
            v4i* dst = reinterpret_cast<v4i*>(lds);
            #pragma unroll
            for (int i = 0; i < PART_WORDS / 4 / THREADS; ++i)   // 4 iters
                dst[i * THREADS + threadIdx.x] = src[i * THREADS + threadIdx.x];
        }
        __syncthreads();

        // Resolve endpoints in this partition (ds_read + predicated add).
        #pragma unroll
        for (int k = 0; k < EPT; ++k) {
            unsigned s = (unsigned)sv[k];
            unsigned ws = lds[(s & (PART_NODES - 1)) >> 4];
            int nts = (int)((ws >> ((s & 15u) << 1)) & 3u);
            if ((s >> PART_BITS) == (unsigned)p) enc[k] += nts * 3;

            unsigned d = (unsigned)dv[k];
            unsigned wd = lds[(d & (PART_NODES - 1)) >> 4];
            int ntd = (int)((wd >> ((d & 15u) << 1)) & 3u);
            if ((d >> PART_BITS) == (unsigned)p) enc[k] += ntd;
        }
        __syncthreads();   // before next fill overwrites the table
    }

    // Node-type table is dead: reuse LDS head for the 450-entry weight table.
    float* lw = reinterpret_cast<float*>(lds);
    for (int i = threadIdx.x; i < TBL; i += THREADS) lw[i] = wtab[i];
    __syncthreads();

    // Per-graph sum. Wave-uniform fast path (batch sorted; a wave's 1024
    // contiguous edges are single-graph most of the time) -> 1 atomic/wave.
    v4i bvv[EPT / 4];
    #pragma unroll
    for (int j = 0; j < EPT / 4; ++j)
        bvv[j] = __builtin_nontemporal_load(reinterpret_cast<const v4i*>(edge_batch + base + j * 4));

    int  b0     = bvv[0][0];
    bool lane_u = (b0 == bvv[EPT / 4 - 1][3]);    // sorted => all equal
    int  wb0    = __shfl(b0, 0);
    int  lane   = threadIdx.x & 63;

    if (__all(lane_u && (b0 == wb0))) {
        float ssum = 0.0f;
        #pragma unroll
        for (int k = 0; k < EPT; ++k) ssum += lw[enc[k]];
        #pragma unroll
        for (int off = 32; off >= 1; off >>= 1)
            ssum += __shfl_down(ssum, off);
        if (lane == 0) atomicAdd(&out[wb0], ssum);
    } else {
        float acc = 0.0f;
        int   cur = -1;
        #pragma unroll
        for (int k = 0; k < EPT; ++k) {
            int bb = bvv[k / 4][k % 4];
            float v = lw[enc[k]];
            if (bb != cur) {
                if (cur >= 0) atomicAdd(&out[cur], acc);
                cur = bb;
                acc = 0.0f;
            }
            acc += v;
        }
        if (cur >= 0) atomicAdd(&out[cur], acc);
    }
}

// Per-edge fallback / tail kernel (direct node_type gathers; correctness path).
__global__ void edge_score_simple(const int* __restrict__ nt,
                                  const int* __restrict__ et,
                                  const int* __restrict__ es,
                                  const int* __restrict__ ed,
                                  const int* __restrict__ eb,
                                  const float* __restrict__ w,
                                  float* __restrict__ out,
                                  long e0, long E) {
    long e = e0 + (long)blockIdx.x * blockDim.x + threadIdx.x;
    if (e >= E) return;
    int enc = et[e] * 9 + nt[es[e]] * 3 + nt[ed[e]];
    atomicAdd(&out[eb[e]], w[enc]);
}

extern "C" void kernel_launch(void* const* d_in, const int* in_sizes, int n_in,
                              void* d_out, int out_size, void* d_ws, size_t ws_size,
                              hipStream_t stream) {
    const int*   node_type  = (const int*)d_in[0];
    const int*   edge_type  = (const int*)d_in[1];
    const int*   edge_index = (const int*)d_in[2];   // [2, E]: src then dst
    const int*   edge_batch = (const int*)d_in[3];
    const float* w          = (const float*)d_in[4];
    float* out = (float*)d_out;

    long N = in_sizes[0];
    long E = in_sizes[1];
    const int* esrc = edge_index;
    const int* edst = edge_index + E;

    // d_out is poisoned once and never re-poisoned between replays; we
    // accumulate with atomics, so zero it at the start of every launch.
    zero_kernel<<<(out_size + 255) / 256, 256, 0, stream>>>(out, out_size);

    int  nwords  = (int)((N + 15) / 16);
    bool fast_ok = (ws_size >= (size_t)nwords * 4) && (N <= (long)NPART * PART_NODES);

    if (fast_ok) {
        unsigned int* pnt = (unsigned int*)d_ws;
        pack_nt_kernel<<<(nwords + 255) / 256, 256, 0, stream>>>(node_type, pnt, nwords, (int)N);

        long nfull = E / WBLK;               // 1024 for E = 2^24
        long rem   = E % WBLK;               // 0 for this dataset
        if (nfull > 0)
            edge_score_lds<<<(int)nfull, THREADS, 0, stream>>>(
                pnt, edge_type, esrc, edst, edge_batch, w, out);
        if (rem > 0) {
            long e0 = nfull * WBLK;
            int  tb = (int)((rem + 255) / 256);
            edge_score_simple<<<tb, 256, 0, stream>>>(
                node_type, edge_type, esrc, edst, edge_batch, w, out, e0, E);
        }
    } else {
        int tb = (int)((E + 255) / 256);
        edge_score_simple<<<tb, 256, 0, stream>>>(
            node_type, edge_type, esrc, edst, edge_batch, w, out, 0, E);
    }
}